// Round 6
// baseline (9013.337 us; speedup 1.0000x reference)
//
#include <hip/hip_runtime.h>
#include <math.h>

// ---------------- problem constants ----------------
#define T_LEN 2048
#define NGRP  16     // batch groups (8 batches each)
#define NSLC  16     // blocks per group (16 hidden/layer/block)
#define BPG   8      // batches per group
#define NTH   512    // 8 waves: w0-3 L0 (wave-private 4-hid tiles), w4-7 L1

typedef __attribute__((ext_vector_type(8))) short short8v;  // 8 bf16
typedef __attribute__((ext_vector_type(4))) float f32x4;
typedef unsigned int u32t;
typedef unsigned long long u64t;

// ---------------- ws layout (u64 units) ----------------
// tagged h element: (tag<<32) | (bf16hi<<16) | bf16lo ; tag = step + 16
// h1(t) lives in slot t&3 with tag t+16 (h2 likewise)
#define H1_OFF  0            // [4 slots][16 grp][8 batch][256 hid] u64 = 131072
#define H2_OFF  131072
#define ABT_OFF 262144
#define WS_U64  262145       // ~2.1 MB

// ---------------- LDS ----------------
// staging: [2 pp][4 planes (h1hi,h1lo,h2hi,h2lo)][16 rows][512 B], XOR-swizzled
// rows 8..15 stay zero forever (BPG=8). 64 KB used; allocate 128 KB -> 1 block/CU.

__device__ __forceinline__ float fsigm(float x) {
  return __builtin_amdgcn_rcpf(1.0f + __builtin_amdgcn_exp2f(-1.44269504f * x));
}
__device__ __forceinline__ float ftanh(float x) {
  // tanh(x) = 1 - 2/(1+e^{2x})
  return fmaf(-2.0f, __builtin_amdgcn_rcpf(1.0f + __builtin_amdgcn_exp2f(2.88539009f * x)), 1.0f);
}

__device__ __forceinline__ u32t bf_rn(float x) {
  u32t b; __builtin_memcpy(&b, &x, 4);
  return (b + 0x7FFFu + ((b >> 16) & 1u)) >> 16;
}
__device__ __forceinline__ void split_bf(float x, u32t& hi, u32t& lo) {
  hi = bf_rn(x);
  u32t hb = hi << 16; float hf; __builtin_memcpy(&hf, &hb, 4);
  lo = bf_rn(x - hf);
}

__global__ void init_ws_kernel(u64t* ws) {
  for (int i = blockIdx.x * blockDim.x + threadIdx.x; i < WS_U64;
       i += gridDim.x * blockDim.x)
    ws[i] = 0ull;
}

#define MFMA16(a, b, c) __builtin_amdgcn_mfma_f32_16x16x32_bf16(a, b, c, 0, 0, 0)
#define LDG(pp, dst) __hip_atomic_load(dst, __ATOMIC_RELAXED, __HIP_MEMORY_SCOPE_AGENT)

__launch_bounds__(NTH, 2)
__global__ void lstm_persist(const float* __restrict__ y,
                             const float* __restrict__ Wih0, const float* __restrict__ Whh0,
                             const float* __restrict__ bih0, const float* __restrict__ bhh0,
                             const float* __restrict__ Wih1, const float* __restrict__ Whh1,
                             const float* __restrict__ bih1, const float* __restrict__ bhh1,
                             const float* __restrict__ Wfc, const float* __restrict__ bfc,
                             float* __restrict__ out, u64t* wsu) {
  extern __shared__ char lds[];
  const int tid   = threadIdx.x;
  const int lane  = tid & 63;
  const int wid   = tid >> 6;
  const int group = blockIdx.x & 15;
  const int slice = blockIdx.x >> 4;

  u64t* h1b    = wsu + H1_OFF;
  u64t* h2b    = wsu + H2_OFF;
  u64t* abortf = wsu + ABT_OFF;

  // zero staging (covers initial h=0 and the permanent zero rows 8..15)
  for (int i = tid; i < 8192; i += NTH) ((u64t*)lds)[i] = 0ull;

  const bool isL1  = (wid >= 4);
  const bool hasFC = (wid == 0 && slice == 0);
  const int  m = lane & 15, kq4 = lane >> 4;
  const int  gate = m & 3, hs4 = m >> 2;           // A row m = hs4*4 + gate
  const int  hidb = slice * 16 + (wid & 3) * 4;
  const int  grow = gate * 256 + hidb + hs4;

  // ---- A-fragment preload (split hi/lo bf16), full K per wave ----
  // L0 waves: ahi[0..7]=Whh0 (ahi[8..15]=Wfc on w0/slice0, else zero)
  // L1 waves: ahi[0..7]=Wih1, ahi[8..15]=Whh1
  const float* WA = isL1 ? Wih1 : Whh0;
  const float* WB = isL1 ? Whh1 : Wfc;
  const int   rowB   = isL1 ? grow : m;
  const bool  bValid = isL1 || (hasFC && m < 2);

  short8v ahi[16], alo[16];
  #pragma unroll
  for (int ks = 0; ks < 8; ++ks) {
    short8v h0, l0, h1, l1;
    #pragma unroll
    for (int j = 0; j < 8; ++j) {
      int k = ks * 32 + kq4 * 8 + j;
      u32t hi, lo;
      split_bf(WA[grow * 256 + k], hi, lo);
      h0[j] = (short)hi; l0[j] = (short)lo;
      float vb = bValid ? WB[rowB * 256 + k] : 0.f;
      split_bf(vb, hi, lo);
      h1[j] = (short)hi; l1[j] = (short)lo;
    }
    ahi[ks] = h0;     alo[ks] = l0;
    ahi[8 + ks] = h1; alo[8 + ks] = l1;
  }

  // ---- per-lane epilogue preloads (C: col=lane&15=batch, row=kq4*4+reg) ----
  const int hidC = hidb + kq4;
  float bias4[4], wx[16];
  #pragma unroll
  for (int r = 0; r < 4; ++r) {
    int row = r * 256 + hidC;
    bias4[r] = isL1 ? (bih1[row] + bhh1[row]) : (bih0[row] + bhh0[row]);
    #pragma unroll
    for (int kk = 0; kk < 4; ++kk)
      wx[r * 4 + kk] = isL1 ? 0.f : Wih0[row * 4 + kk];
  }
  float bfc0 = 0.f, bfc1 = 0.f;
  if (hasFC) { bfc0 = bfc[0]; bfc1 = bfc[1]; }
  const float* yb = y + (group * BPG + (m & 7)) * T_LEN;

  float cst = 0.f;   // lane-local cell state (c1 on w0-3, c2 on w4-7)

  // staging map: thread -> (batch row srow, 4 consecutive hid elements)
  const int srow = tid >> 6;             // 0..7
  const int sc4  = (tid & 63) * 4;       // hid base (u64/elem units)
  const int soff = srow * 512 + ((sc4 * 2) ^ (srow << 4));   // byte, swizzled
  // B-read map
  const int brow = lane & 15;
  const int bxr  = (brow & 7) << 4;
  const int bco  = kq4 * 16;

  __syncthreads();

  for (int p = 0; p <= T_LEN + 1; ++p) {
    const int  pp    = p & 1;
    const bool need1 = (p >= 1 && p <= T_LEN);   // h1(p-1)
    const bool need2 = (p >= 2);                 // h2(p-2)

    // ---- y prefetch (off exchange path) ----
    float xx[4];
    if (!isL1 && p < T_LEN) {
      #pragma unroll
      for (int kk = 0; kk < 4; ++kk) {
        int ti = p + kk - 3;
        xx[kk] = (ti >= 0) ? yb[ti] : -100.0f;
      }
    }

    // ---- S1: tagged poll+load (single propagation; backoff on retry) ----
    u64t v1[4], v2[4];
    {
      const u64t* s1 = h1b + (u64t)((p - 1) & 3) * (NGRP * 2048) + group * 2048 + srow * 256 + sc4;
      const u64t* s2 = h2b + (u64t)((p - 2) & 3) * (NGRP * 2048) + group * 2048 + srow * 256 + sc4;
      const u32t tg1 = (u32t)(p + 15), tg2 = (u32t)(p + 14);
      u32t st1 = 0u, st2 = 0u;
      if (need1) {
        #pragma unroll
        for (int j = 0; j < 4; ++j)
          v1[j] = __hip_atomic_load(s1 + j, __ATOMIC_RELAXED, __HIP_MEMORY_SCOPE_AGENT);
        #pragma unroll
        for (int j = 0; j < 4; ++j)
          if ((u32t)(v1[j] >> 32) != tg1) st1 |= 1u << j;
      }
      if (need2) {
        #pragma unroll
        for (int j = 0; j < 4; ++j)
          v2[j] = __hip_atomic_load(s2 + j, __ATOMIC_RELAXED, __HIP_MEMORY_SCOPE_AGENT);
        #pragma unroll
        for (int j = 0; j < 4; ++j)
          if ((u32t)(v2[j] >> 32) != tg2) st2 |= 1u << j;
      }
      int guard = 0;
      while (st1 | st2) {
        __builtin_amdgcn_s_sleep(1);   // backoff BEFORE re-poll (anti-congestion)
        #pragma unroll
        for (int j = 0; j < 4; ++j)
          if (st1 & (1u << j))
            v1[j] = __hip_atomic_load(s1 + j, __ATOMIC_RELAXED, __HIP_MEMORY_SCOPE_AGENT);
        #pragma unroll
        for (int j = 0; j < 4; ++j)
          if (st2 & (1u << j))
            v2[j] = __hip_atomic_load(s2 + j, __ATOMIC_RELAXED, __HIP_MEMORY_SCOPE_AGENT);
        u32t n1 = 0, n2 = 0;
        #pragma unroll
        for (int j = 0; j < 4; ++j)
          if ((st1 & (1u << j)) && (u32t)(v1[j] >> 32) != tg1) n1 |= 1u << j;
        #pragma unroll
        for (int j = 0; j < 4; ++j)
          if ((st2 & (1u << j)) && (u32t)(v2[j] >> 32) != tg2) n2 |= 1u << j;
        st1 = n1; st2 = n2;
        if (st1 | st2) {
          if (++guard > (1 << 15)) {
            __hip_atomic_store(abortf, 1ull, __ATOMIC_RELAXED, __HIP_MEMORY_SCOPE_AGENT);
            break;
          }
          if ((guard & 31) == 0 &&
              __hip_atomic_load(abortf, __ATOMIC_RELAXED, __HIP_MEMORY_SCOPE_AGENT) != 0)
            break;
        }
      }
    }

    // ---- unpack to swizzled LDS planes (pp buffer) ----
    {
      char* sbase = lds + pp * 32768;
      if (need1) {
        u64t hw = 0, lw = 0;
        #pragma unroll
        for (int j = 0; j < 4; ++j) {
          u32t pk = (u32t)v1[j];
          hw |= (u64t)(pk >> 16) << (16 * j);
          lw |= (u64t)(pk & 0xFFFFu) << (16 * j);
        }
        *(u64t*)(sbase + soff)        = hw;
        *(u64t*)(sbase + 8192 + soff) = lw;
      }
      if (need2) {
        u64t hw = 0, lw = 0;
        #pragma unroll
        for (int j = 0; j < 4; ++j) {
          u32t pk = (u32t)v2[j];
          hw |= (u64t)(pk >> 16) << (16 * j);
          lw |= (u64t)(pk & 0xFFFFu) << (16 * j);
        }
        *(u64t*)(sbase + 16384 + soff) = hw;
        *(u64t*)(sbase + 24576 + soff) = lw;
      }
    }
    __syncthreads();   // the ONLY barrier per phase

    // ---- MFMA (3-term split precision, 2 independent acc chains) ----
    const char* sb = lds + pp * 32768;
#define BRD(pl, ks) (*(const short8v*)(sb + (pl) * 8192 + brow * 512 + ((((ks) * 64) + bco) ^ bxr)))

    const bool act = isL1 ? need1 : (p < T_LEN);
    f32x4 accP = {0.f, 0.f, 0.f, 0.f}, accQ = {0.f, 0.f, 0.f, 0.f};
    if (act) {
      if (!isL1) {
        #pragma unroll
        for (int ks = 0; ks < 8; ++ks) {
          short8v bh = BRD(0, ks), bl = BRD(1, ks);
          accP = MFMA16(ahi[ks], bh, accP);
          accQ = MFMA16(ahi[ks], bl, accQ);
          accQ = MFMA16(alo[ks], bh, accQ);
        }
      } else {
        #pragma unroll
        for (int ks = 0; ks < 8; ++ks) {
          short8v b1h = BRD(0, ks), b1l = BRD(1, ks);
          short8v b2h = BRD(2, ks), b2l = BRD(3, ks);
          accP = MFMA16(ahi[ks], b1h, accP);
          accQ = MFMA16(ahi[ks], b1l, accQ);
          accQ = MFMA16(alo[ks], b1h, accQ);
          accP = MFMA16(ahi[8 + ks], b2h, accP);
          accQ = MFMA16(ahi[8 + ks], b2l, accQ);
          accQ = MFMA16(alo[8 + ks], b2h, accQ);
        }
      }
    }

    // ---- finisher (same wave): nonlin + c update + tagged h store ----
    if (act) {
      float g[4];
      #pragma unroll
      for (int r = 0; r < 4; ++r) g[r] = accP[r] + accQ[r] + bias4[r];
      if (!isL1) {
        #pragma unroll
        for (int kk = 0; kk < 4; ++kk)
          #pragma unroll
          for (int r = 0; r < 4; ++r) g[r] = fmaf(wx[r * 4 + kk], xx[kk], g[r]);
      }
      cst = fsigm(g[1]) * cst + fsigm(g[0]) * ftanh(g[2]);
      float hv = fsigm(g[3]) * ftanh(cst);
      if (m < BPG) {
        u32t hi, lo; split_bf(hv, hi, lo);
        const u32t tag = (u32t)(isL1 ? (p + 15) : (p + 16));
        u64t w = ((u64t)tag << 32) | (u64t)((hi << 16) | lo);
        u64t* dst = isL1
            ? (h2b + (u64t)((p - 1) & 3) * (NGRP * 2048) + group * 2048 + m * 256 + hidC)
            : (h1b + (u64t)(p & 3) * (NGRP * 2048) + group * 2048 + m * 256 + hidC);
        __hip_atomic_store(dst, w, __ATOMIC_RELAXED, __HIP_MEMORY_SCOPE_AGENT);
        // fire-and-forget: tag carries validity; no vmcnt, no flag
      }
    }

    // ---- FC (w0/slice0 only, AFTER h1 store so it's off the critical path) ----
    if (hasFC && need2) {
      f32x4 aF = {0.f, 0.f, 0.f, 0.f}, aG = {0.f, 0.f, 0.f, 0.f};
      #pragma unroll
      for (int ks = 0; ks < 8; ++ks) {
        short8v b2h = BRD(2, ks), b2l = BRD(3, ks);
        aF = MFMA16(ahi[8 + ks], b2h, aF);
        aG = MFMA16(ahi[8 + ks], b2l, aG);
        aG = MFMA16(alo[8 + ks], b2h, aG);
      }
      if (lane < 8) {
        float2 o;
        o.x = aF[0] + aG[0] + bfc0;
        o.y = aF[1] + aG[1] + bfc1;
        *(float2*)(&out[(group * BPG + lane) * (T_LEN * 2) + (p - 2) * 2]) = o;
      }
    }
  }
}

extern "C" void kernel_launch(void* const* d_in, const int* in_sizes, int n_in,
                              void* d_out, int out_size, void* d_ws, size_t ws_size,
                              hipStream_t stream) {
  const float* y    = (const float*)d_in[0];
  const float* Wih0 = (const float*)d_in[1];
  const float* Whh0 = (const float*)d_in[2];
  const float* bih0 = (const float*)d_in[3];
  const float* bhh0 = (const float*)d_in[4];
  const float* Wih1 = (const float*)d_in[5];
  const float* Whh1 = (const float*)d_in[6];
  const float* bih1 = (const float*)d_in[7];
  const float* bhh1 = (const float*)d_in[8];
  const float* Wfc  = (const float*)d_in[9];
  const float* bfc  = (const float*)d_in[10];
  float* out = (float*)d_out;
  u64t*  ws  = (u64t*)d_ws;

  (void)hipFuncSetAttribute(reinterpret_cast<const void*>(lstm_persist),
                            hipFuncAttributeMaxDynamicSharedMemorySize, 131072);

  hipLaunchKernelGGL(init_ws_kernel, dim3(256), dim3(256), 0, stream, ws);
  hipLaunchKernelGGL(lstm_persist, dim3(NGRP * NSLC), dim3(NTH), 131072, stream,
                     y, Wih0, Whh0, bih0, bhh0, Wih1, Whh1, bih1, bhh1,
                     Wfc, bfc, out, ws);
}

// Round 8
// 7834.003 us; speedup vs baseline: 1.1505x; 1.1505x over previous
//
#include <hip/hip_runtime.h>
#include <math.h>

// ---------------- problem constants ----------------
#define T_LEN 2048
#define NGRP  32     // batch groups (4 batches each)
#define NSLC  16     // blocks per (group,slice) grid dim; 16 hidden/layer/block
#define BPG   4      // batches per group
#define NTH   512    // 8 waves: w0-3 L0 (wave-private 4-hid tiles), w4-7 L1
// each block serves TWO groups: gA = blockIdx>>4 (0..15), gB = gA+16

typedef __attribute__((ext_vector_type(8))) short short8v;  // 8 bf16
typedef __attribute__((ext_vector_type(4))) float f32x4;
typedef unsigned int u32t;
typedef unsigned long long u64t;

// ---------------- ws layout (u64 units) ----------------
// tagged h element: (tag<<32) | (bf16hi<<16) | bf16lo ; h(step s) in slot s&3, tag s+16
#define H1_OFF  0            // [4 slots][32 grp][4 batch][256 hid] u64 = 131072
#define H2_OFF  131072
#define ABT_OFF 262144
#define WS_U64  262145       // ~2.1 MB

// ---------------- LDS ----------------
// context c (0/1) at c*65536: [2 pp][4 planes (h1hi,h1lo,h2hi,h2lo)][16 rows][512 B]
// rows 4..15 permanently zero (BPG=4). 128 KB total -> exactly 1 block/CU.

__device__ __forceinline__ float fsigm(float x) {
  return __builtin_amdgcn_rcpf(1.0f + __builtin_amdgcn_exp2f(-1.44269504f * x));
}
__device__ __forceinline__ float ftanh(float x) {
  return fmaf(-2.0f, __builtin_amdgcn_rcpf(1.0f + __builtin_amdgcn_exp2f(2.88539009f * x)), 1.0f);
}

__device__ __forceinline__ u32t bf_rn(float x) {
  u32t b; __builtin_memcpy(&b, &x, 4);
  return (b + 0x7FFFu + ((b >> 16) & 1u)) >> 16;
}
__device__ __forceinline__ void split_bf(float x, u32t& hi, u32t& lo) {
  hi = bf_rn(x);
  u32t hb = hi << 16; float hf; __builtin_memcpy(&hf, &hb, 4);
  lo = bf_rn(x - hf);
}

__global__ void init_ws_kernel(u64t* ws) {
  for (int i = blockIdx.x * blockDim.x + threadIdx.x; i < WS_U64;
       i += gridDim.x * blockDim.x)
    ws[i] = 0ull;
}

#define MFMA16(a, b, c) __builtin_amdgcn_mfma_f32_16x16x32_bf16(a, b, c, 0, 0, 0)
#define ALD(ptr) __hip_atomic_load(ptr, __ATOMIC_RELAXED, __HIP_MEMORY_SCOPE_AGENT)

__launch_bounds__(NTH, 2)
__global__ void lstm_persist(const float* __restrict__ y,
                             const float* __restrict__ Wih0, const float* __restrict__ Whh0,
                             const float* __restrict__ bih0, const float* __restrict__ bhh0,
                             const float* __restrict__ Wih1, const float* __restrict__ Whh1,
                             const float* __restrict__ bih1, const float* __restrict__ bhh1,
                             const float* __restrict__ Wfc, const float* __restrict__ bfc,
                             float* __restrict__ out, u64t* wsu) {
  extern __shared__ char lds[];
  const int tid   = threadIdx.x;
  const int lane  = tid & 63;
  const int wid   = tid >> 6;
  const int slice = blockIdx.x & 15;
  const int gA    = blockIdx.x >> 4;   // 0..15
  const int gB    = gA + 16;           // 16..31

  u64t* h1b    = wsu + H1_OFF;
  u64t* h2b    = wsu + H2_OFF;
  u64t* abortf = wsu + ABT_OFF;

  // zero both contexts' staging (initial h = 0; rows 4..15 permanently zero)
  for (int i = tid; i < 16384; i += NTH) ((u64t*)lds)[i] = 0ull;

  const bool isL1 = (wid >= 4);
  const int  m = lane & 15, kq4 = lane >> 4;
  const int  gate = m & 3, hs4 = m >> 2;           // A row m = hs4*4 + gate
  const int  hidb = slice * 16 + (wid & 3) * 4;
  const int  grow = gate * 256 + hidb + hs4;

  // ---- A-fragment preload (split hi/lo bf16); SHARED by both contexts ----
  // L0 waves: ahi[0..7]=Whh0; w0 also ahi[8..15]=Wfc (FC rotates over slices)
  // L1 waves: ahi[0..7]=Wih1, ahi[8..15]=Whh1
  const float* WA = isL1 ? Wih1 : Whh0;
  const float* WB = isL1 ? Whh1 : Wfc;
  const int   rowB   = isL1 ? grow : m;
  const bool  bValid = isL1 || (wid == 0 && m < 2);

  short8v ahi[16], alo[16];
  #pragma unroll
  for (int ks = 0; ks < 8; ++ks) {
    short8v h0, l0, h1, l1;
    #pragma unroll
    for (int j = 0; j < 8; ++j) {
      int k = ks * 32 + kq4 * 8 + j;
      u32t hi, lo;
      split_bf(WA[grow * 256 + k], hi, lo);
      h0[j] = (short)hi; l0[j] = (short)lo;
      float vb = bValid ? WB[rowB * 256 + k] : 0.f;
      split_bf(vb, hi, lo);
      h1[j] = (short)hi; l1[j] = (short)lo;
    }
    ahi[ks] = h0;     alo[ks] = l0;
    ahi[8 + ks] = h1; alo[8 + ks] = l1;
  }

  // ---- per-lane epilogue preloads (C: col=lane&15=batch, row=kq4*4+reg) ----
  const int hidC = hidb + kq4;
  float bias4[4], wx[16];
  #pragma unroll
  for (int r = 0; r < 4; ++r) {
    int row = r * 256 + hidC;
    bias4[r] = isL1 ? (bih1[row] + bhh1[row]) : (bih0[row] + bhh0[row]);
    #pragma unroll
    for (int kk = 0; kk < 4; ++kk)
      wx[r * 4 + kk] = isL1 ? 0.f : Wih0[row * 4 + kk];
  }
  float bfc0 = 0.f, bfc1 = 0.f;
  if (wid == 0) { bfc0 = bfc[0]; bfc1 = bfc[1]; }
  const float* ybA = y + (gA * BPG + (m & 3)) * T_LEN;
  const float* ybB = y + (gB * BPG + (m & 3)) * T_LEN;

  float cstA = 0.f, cstB = 0.f;   // per-context lane-local cell state

  // staging map: thread -> (batch row srow 0..3, 2 consecutive hid elements)
  const int srow = tid >> 7;
  const int sc2  = (tid & 127) * 2;                          // elem base
  const int soff = srow * 512 + (((tid & 127) * 4) ^ (srow << 4));  // byte, swizzled
  // B-read map
  const int brow = lane & 15;
  const int bxr  = (brow & 7) << 4;
  const int bco  = kq4 * 16;

  u64t vA1[2], vA2[2], vB1[2], vB2[2];

  // ---- issue tagged loads for context G at phase p (prefetch; checked later) ----
  auto issue = [&](int G, int p, u64t* v1, u64t* v2) {
    if (p >= 1 && p <= T_LEN) {
      const u64t* s1 = h1b + (u64t)((p - 1) & 3) * (NGRP * 1024) + G * 1024 + srow * 256 + sc2;
      v1[0] = ALD(s1); v1[1] = ALD(s1 + 1);
    }
    if (p >= 2) {
      const u64t* s2 = h2b + (u64t)((p - 2) & 3) * (NGRP * 1024) + G * 1024 + srow * 256 + sc2;
      v2[0] = ALD(s2); v2[1] = ALD(s2 + 1);
    }
  };

  // ---- validate tags (retry stale with backoff), unpack into LDS planes ----
  auto check_unpack = [&](char* LB, int G, int p, u64t* v1, u64t* v2) {
    const bool need1 = (p >= 1 && p <= T_LEN);
    const bool need2 = (p >= 2);
    const u64t* s1 = h1b + (u64t)((p - 1) & 3) * (NGRP * 1024) + G * 1024 + srow * 256 + sc2;
    const u64t* s2 = h2b + (u64t)((p - 2) & 3) * (NGRP * 1024) + G * 1024 + srow * 256 + sc2;
    const u32t tg1 = (u32t)(p + 15), tg2 = (u32t)(p + 14);
    u32t st = 0;
    if (need1) {
      if ((u32t)(v1[0] >> 32) != tg1) st |= 1u;
      if ((u32t)(v1[1] >> 32) != tg1) st |= 2u;
    }
    if (need2) {
      if ((u32t)(v2[0] >> 32) != tg2) st |= 4u;
      if ((u32t)(v2[1] >> 32) != tg2) st |= 8u;
    }
    int guard = 0;
    while (st) {
      __builtin_amdgcn_s_sleep(1);   // backoff before re-poll (anti-congestion)
      if (st & 1u) v1[0] = ALD(s1);
      if (st & 2u) v1[1] = ALD(s1 + 1);
      if (st & 4u) v2[0] = ALD(s2);
      if (st & 8u) v2[1] = ALD(s2 + 1);
      u32t n = 0;
      if ((st & 1u) && (u32t)(v1[0] >> 32) != tg1) n |= 1u;
      if ((st & 2u) && (u32t)(v1[1] >> 32) != tg1) n |= 2u;
      if ((st & 4u) && (u32t)(v2[0] >> 32) != tg2) n |= 4u;
      if ((st & 8u) && (u32t)(v2[1] >> 32) != tg2) n |= 8u;
      st = n;
      if (st) {
        if (++guard > (1 << 15)) {
          __hip_atomic_store(abortf, 1ull, __ATOMIC_RELAXED, __HIP_MEMORY_SCOPE_AGENT);
          break;
        }
        if ((guard & 31) == 0 &&
            __hip_atomic_load(abortf, __ATOMIC_RELAXED, __HIP_MEMORY_SCOPE_AGENT) != 0)
          break;
      }
    }
    char* sbase = LB + (p & 1) * 32768;
    if (need1) {
      u32t e0 = (u32t)v1[0], e1 = (u32t)v1[1];
      *(u32t*)(sbase + soff)        = (e0 >> 16) | (e1 & 0xFFFF0000u);
      *(u32t*)(sbase + 8192 + soff) = (e0 & 0xFFFFu) | (e1 << 16);
    }
    if (need2) {
      u32t e0 = (u32t)v2[0], e1 = (u32t)v2[1];
      *(u32t*)(sbase + 16384 + soff) = (e0 >> 16) | (e1 & 0xFFFF0000u);
      *(u32t*)(sbase + 24576 + soff) = (e0 & 0xFFFFu) | (e1 << 16);
    }
  };

#define BRD(sb, pl, ks) \
  (*(const short8v*)((sb) + (pl) * 8192 + brow * 512 + ((((ks) * 64) + bco) ^ bxr)))

  // ---- MFMA + finisher + tagged store + rotated FC for one context ----
  auto compute_fin = [&](char* LB, int G, int p, float& cst, const float* yb) {
    const bool need1 = (p >= 1 && p <= T_LEN);
    const bool act = isL1 ? need1 : (p < T_LEN);
    const char* sb = LB + (p & 1) * 32768;
    f32x4 accP = {0.f, 0.f, 0.f, 0.f}, accQ = {0.f, 0.f, 0.f, 0.f};
    if (act) {
      if (!isL1) {
        #pragma unroll
        for (int ks = 0; ks < 8; ++ks) {
          short8v bh = BRD(sb, 0, ks), bl = BRD(sb, 1, ks);
          accP = MFMA16(ahi[ks], bh, accP);
          accQ = MFMA16(ahi[ks], bl, accQ);
          accQ = MFMA16(alo[ks], bh, accQ);
        }
      } else {
        #pragma unroll
        for (int ks = 0; ks < 8; ++ks) {
          short8v b1h = BRD(sb, 0, ks), b1l = BRD(sb, 1, ks);
          short8v b2h = BRD(sb, 2, ks), b2l = BRD(sb, 3, ks);
          accP = MFMA16(ahi[ks], b1h, accP);
          accQ = MFMA16(ahi[ks], b1l, accQ);
          accQ = MFMA16(alo[ks], b1h, accQ);
          accP = MFMA16(ahi[8 + ks], b2h, accP);
          accQ = MFMA16(ahi[8 + ks], b2l, accQ);
          accQ = MFMA16(alo[8 + ks], b2h, accQ);
        }
      }
      float g[4];
      #pragma unroll
      for (int r = 0; r < 4; ++r) g[r] = accP[r] + accQ[r] + bias4[r];
      if (!isL1) {
        float xx[4];
        #pragma unroll
        for (int kk = 0; kk < 4; ++kk) {
          int ti = p + kk - 3;
          xx[kk] = (ti >= 0) ? yb[ti] : -100.0f;
        }
        #pragma unroll
        for (int kk = 0; kk < 4; ++kk)
          #pragma unroll
          for (int r = 0; r < 4; ++r) g[r] = fmaf(wx[r * 4 + kk], xx[kk], g[r]);
      }
      cst = fsigm(g[1]) * cst + fsigm(g[0]) * ftanh(g[2]);
      float hv = fsigm(g[3]) * ftanh(cst);
      if (m < BPG) {
        u32t hi, lo; split_bf(hv, hi, lo);
        const u32t tag = (u32t)(isL1 ? (p + 15) : (p + 16));
        u64t w = ((u64t)tag << 32) | (u64t)((hi << 16) | lo);
        u64t* dst = isL1
            ? (h2b + (u64t)((p - 1) & 3) * (NGRP * 1024) + G * 1024 + m * 256 + hidC)
            : (h1b + (u64t)(p & 3) * (NGRP * 1024) + G * 1024 + m * 256 + hidC);
        __hip_atomic_store(dst, w, __ATOMIC_RELAXED, __HIP_MEMORY_SCOPE_AGENT);
        // fire-and-forget: tag carries validity
      }
    }
    // FC: rotated across slices; step s = p-2 handled by slice s&15
    if (wid == 0 && p >= 2 && slice == ((p - 2) & 15)) {
      f32x4 aF = {0.f, 0.f, 0.f, 0.f}, aG = {0.f, 0.f, 0.f, 0.f};
      #pragma unroll
      for (int ks = 0; ks < 8; ++ks) {
        short8v b2h = BRD(sb, 2, ks), b2l = BRD(sb, 3, ks);
        aF = MFMA16(ahi[8 + ks], b2h, aF);
        aG = MFMA16(ahi[8 + ks], b2l, aG);
        aG = MFMA16(alo[8 + ks], b2h, aG);
      }
      if (lane < BPG) {
        float2 o;
        o.x = aF[0] + aG[0] + bfc0;
        o.y = aF[1] + aG[1] + bfc1;
        *(float2*)(&out[(G * BPG + lane) * (T_LEN * 2) + (p - 2) * 2]) = o;
      }
    }
  };

  __syncthreads();

  for (int p = 0; p <= T_LEN + 1; ++p) {
    // ---- context A ----
    check_unpack(lds, gA, p, vA1, vA2);
    __syncthreads();                       // staging A visible
    issue(gB, p, vB1, vB2);                // B's loads fly under A's compute
    compute_fin(lds, gA, p, cstA, ybA);
    // ---- context B ----
    check_unpack(lds + 65536, gB, p, vB1, vB2);
    __syncthreads();                       // staging B visible
    if (p <= T_LEN) issue(gA, p + 1, vA1, vA2);  // A's next loads fly under B's compute
    compute_fin(lds + 65536, gB, p, cstB, ybB);
  }
}

extern "C" void kernel_launch(void* const* d_in, const int* in_sizes, int n_in,
                              void* d_out, int out_size, void* d_ws, size_t ws_size,
                              hipStream_t stream) {
  const float* y    = (const float*)d_in[0];
  const float* Wih0 = (const float*)d_in[1];
  const float* Whh0 = (const float*)d_in[2];
  const float* bih0 = (const float*)d_in[3];
  const float* bhh0 = (const float*)d_in[4];
  const float* Wih1 = (const float*)d_in[5];
  const float* Whh1 = (const float*)d_in[6];
  const float* bih1 = (const float*)d_in[7];
  const float* bhh1 = (const float*)d_in[8];
  const float* Wfc  = (const float*)d_in[9];
  const float* bfc  = (const float*)d_in[10];
  float* out = (float*)d_out;
  u64t*  ws  = (u64t*)d_ws;

  (void)hipFuncSetAttribute(reinterpret_cast<const void*>(lstm_persist),
                            hipFuncAttributeMaxDynamicSharedMemorySize, 131072);

  hipLaunchKernelGGL(init_ws_kernel, dim3(256), dim3(256), 0, stream, ws);
  hipLaunchKernelGGL(lstm_persist, dim3(NGRP / 2 * NSLC), dim3(NTH), 131072, stream,
                     y, Wih0, Whh0, bih0, bhh0, Wih1, Whh1, bih1, bhh1,
                     Wfc, bfc, out, ws);
}